// Round 3
// baseline (1774.734 us; speedup 1.0000x reference)
//
#include <hip/hip_runtime.h>
#include <hip/hip_bf16.h>

// ---------------------------------------------------------------------------
// SCCNN forward, MI355X. Split-bf16 (hi+lo) MFMA GEMMs, fully LDS-free:
//   A fragments: direct coalesced f32 global loads + in-register RNE split.
//   X operands:  pre-split + pre-transposed bf16 (h/l) read straight into
//                B-fragments (16B/lane) from L2/L3.
//   Split-K via plain partials buffer + fused reduce/split-transpose kernel.
// Pipeline:
//   RHS = [B1@x1 | x0];  Y = Richardson^8 (y <- RHS + (I-D1)y)  -> [x0p | z]
//   C10 = L0@[x0|x0p]; C20 = 2*L0@C10 - [x0|x0p]
//   W = B1^T@z; V1 = D2@W; C11 = L1l@[V1|x1]; C21 = 2*L1l@C11 - [V1|x1]
//   y0 = relu(einsum), y1 = relu(einsum)
// Round-2 delta: gemm_sp blocks 256->128 threads (2 waves) for even CU
// spread of the HBM-bound A reads; semantics unchanged.
// ---------------------------------------------------------------------------

typedef __attribute__((ext_vector_type(8))) short short8v;
typedef __attribute__((ext_vector_type(8))) unsigned short ushort8v;
typedef __attribute__((ext_vector_type(4))) float float4v;

__device__ __forceinline__ unsigned short f2bf(float v) {
  __hip_bfloat16 h = __float2bfloat16(v);               // RNE
  return __builtin_bit_cast(unsigned short, h);
}
__device__ __forceinline__ float bf2f(unsigned short u) {
  __hip_bfloat16 h = __builtin_bit_cast(__hip_bfloat16, u);
  return __bfloat162float(h);
}
__device__ __forceinline__ void split2(float v, unsigned short& h, unsigned short& l) {
  h = f2bf(v);
  float r = v - bf2f(h);
  l = f2bf(r);
}

// ---------------------------------------------------------------------------
// gemm_sp: P[s][m][0..F) = op(A)[m, k0:k1) @ X[k0:k1, 0..F)   (partials)
//   op(A)=A (M x K, lda) if !TA, else op(A)[m][k] = A[k*lda + m].
//   IMINUS: use (I - A) instead of A (for Richardson).
//   X given as split/transposed bf16: xh/xl [col][k] with leading dim ldt;
//   cols 0..31 from (xh0,xl0), cols 32..63 from (xh1,xl1).
//   Block: 128 thr = 2 waves; wave w owns rows m0+w*64 .. +64 (64 x F tile).
// ---------------------------------------------------------------------------
template<int F, bool TA, bool IMINUS>
__launch_bounds__(128, 2)
__global__ void gemm_sp(const float* __restrict__ A, int lda, int M, int K,
                        const unsigned short* __restrict__ xh0, const unsigned short* __restrict__ xl0,
                        const unsigned short* __restrict__ xh1, const unsigned short* __restrict__ xl1,
                        int ldt, float* __restrict__ P, int kchunk) {
  constexpr int NF = F / 16;
  const int tid  = threadIdx.x;
  const int lane = tid & 63;
  const int wave = tid >> 6;
  const int l15  = lane & 15;
  const int g    = lane >> 4;               // k-group 0..3
  const int m0   = blockIdx.x * 128 + wave * 64;
  const int s    = blockIdx.y;
  const int kk0  = s * kchunk;
  if (kk0 >= K) return;
  const int k1   = min(K, kk0 + kchunk);

  const unsigned short* xb_h[NF];
  const unsigned short* xb_l[NF];
#pragma unroll
  for (int nf = 0; nf < NF; ++nf) {
    int c = 16 * nf + l15;
    if (nf < 2) { xb_h[nf] = xh0 + (size_t)c * ldt;        xb_l[nf] = xl0 + (size_t)c * ldt; }
    else        { xb_h[nf] = xh1 + (size_t)(c - 32) * ldt; xb_l[nf] = xl1 + (size_t)(c - 32) * ldt; }
  }

  float4v acc[4][NF];
#pragma unroll
  for (int i = 0; i < 4; ++i)
#pragma unroll
    for (int j = 0; j < NF; ++j)
#pragma unroll
      for (int r = 0; r < 4; ++r) acc[i][j][r] = 0.f;

  for (int kt = kk0; kt < k1; kt += 32) {
    const int kb = kt + 8 * g;
    const bool full = (kt + 32 <= k1);

    // ---- X fragments (B operand): lane holds X[kb+j][col], 16B contiguous ----
    short8v xh[NF], xl[NF];
    if (full) {
#pragma unroll
      for (int nf = 0; nf < NF; ++nf) {
        xh[nf] = *(const short8v*)(xb_h[nf] + kb);
        xl[nf] = *(const short8v*)(xb_l[nf] + kb);
      }
    } else {
#pragma unroll
      for (int nf = 0; nf < NF; ++nf)
#pragma unroll
        for (int j = 0; j < 8; ++j) {
          int k = kb + j;
          xh[nf][j] = (k < k1) ? (short)xb_h[nf][k] : (short)0;
          xl[nf][j] = (k < k1) ? (short)xb_l[nf][k] : (short)0;
        }
    }

    // ---- per m-frag: load A row chunk, split, 3*NF MFMAs ----
#pragma unroll
    for (int mf = 0; mf < 4; ++mf) {
      const int grow = m0 + 16 * mf + l15;     // A-frag row = lane%16
      const int r = min(grow, M - 1);          // clamp (stores guarded)
      float av[8];
      if (!TA) {
        const float* ap = A + (size_t)r * lda + kb;
        if (full) {
          float4 t0 = *(const float4*)(ap);
          float4 t1 = *(const float4*)(ap + 4);
          av[0]=t0.x; av[1]=t0.y; av[2]=t0.z; av[3]=t0.w;
          av[4]=t1.x; av[5]=t1.y; av[6]=t1.z; av[7]=t1.w;
        } else {
#pragma unroll
          for (int j = 0; j < 8; ++j) { int k = kb + j; av[j] = (k < k1) ? ap[j] : 0.f; }
        }
      } else {
#pragma unroll
        for (int j = 0; j < 8; ++j) {
          int k = kb + j;
          av[j] = (k < k1) ? A[(size_t)k * lda + r] : 0.f;
        }
      }
      if (IMINUS) {
#pragma unroll
        for (int j = 0; j < 8; ++j) {
          int k = kb + j;
          av[j] = (k < k1) ? (((k == grow) ? 1.f : 0.f) - av[j]) : 0.f;
        }
      }
      short8v ah, al;
#pragma unroll
      for (int j = 0; j < 8; ++j) {
        unsigned short h, l; split2(av[j], h, l);
        ah[j] = (short)h; al[j] = (short)l;
      }
#pragma unroll
      for (int nf = 0; nf < NF; ++nf) {
        acc[mf][nf] = __builtin_amdgcn_mfma_f32_16x16x32_bf16(ah, xh[nf], acc[mf][nf], 0, 0, 0);
        acc[mf][nf] = __builtin_amdgcn_mfma_f32_16x16x32_bf16(ah, xl[nf], acc[mf][nf], 0, 0, 0);
        acc[mf][nf] = __builtin_amdgcn_mfma_f32_16x16x32_bf16(al, xh[nf], acc[mf][nf], 0, 0, 0);
      }
    }
  }

  // ---- epilogue: D[row = 4*g + r (+16*mf)][col = l15 (+16*nf)] ----
  float* Pb = P + (size_t)s * M * F;
#pragma unroll
  for (int mf = 0; mf < 4; ++mf)
#pragma unroll
    for (int r4 = 0; r4 < 4; ++r4) {
      int row = m0 + 16 * mf + 4 * g + r4;
      if (row < M) {
#pragma unroll
        for (int nf = 0; nf < NF; ++nf)
          Pb[(size_t)row * F + 16 * nf + l15] = acc[mf][nf][r4];
      }
    }
}

// ---------------------------------------------------------------------------
// reduce_splitT: C[m][f] = alpha * sum_s P[s][m][f<Fp] + beta * bias
//   bias: cols 0..31 from bA (ldA), cols 32..63 from bB (ldB). Nullable.
//   Optional f32 out Cout (ld=FO); optional transposed split out Th/Tl
//   ([f][m], leading dim ldt) for use as the next GEMM's X operand.
// ---------------------------------------------------------------------------
template<int FO>
__global__ void reduce_splitT(const float* __restrict__ P, int Fp, int S, int M,
                              float alpha,
                              const float* __restrict__ bA, int ldA,
                              const float* __restrict__ bB, int ldB, float beta,
                              float* __restrict__ Cout,
                              unsigned short* __restrict__ Th, unsigned short* __restrict__ Tl,
                              int ldt) {
  __shared__ float Ts[64][FO + 4];
  const int tid = threadIdx.x;
  const int m0 = blockIdx.x * 64;
  constexpr int PASSES = (64 * FO) / 1024;
#pragma unroll
  for (int p = 0; p < PASSES; ++p) {
    int e  = p * 1024 + tid * 4;
    int ml = e / FO;
    int f  = e % FO;
    int m  = m0 + ml;
    float vx = 0.f, vy = 0.f, vz = 0.f, vw = 0.f;
    if (m < M) {
      if (f < Fp) {
        for (int s = 0; s < S; ++s) {
          const float4 pv = *(const float4*)(P + ((size_t)s * M + m) * Fp + f);
          vx += pv.x; vy += pv.y; vz += pv.z; vw += pv.w;
        }
        vx *= alpha; vy *= alpha; vz *= alpha; vw *= alpha;
      }
      if (beta != 0.f) {
        if (f < 32) {
          if (bA) { const float4 b = *(const float4*)(bA + (size_t)m * ldA + f);
                    vx += beta*b.x; vy += beta*b.y; vz += beta*b.z; vw += beta*b.w; }
        } else {
          if (bB) { const float4 b = *(const float4*)(bB + (size_t)m * ldB + (f - 32));
                    vx += beta*b.x; vy += beta*b.y; vz += beta*b.z; vw += beta*b.w; }
        }
      }
      if (Cout) { float4 o = make_float4(vx, vy, vz, vw);
                  *(float4*)(Cout + (size_t)m * FO + f) = o; }
    }
    Ts[ml][f+0] = vx; Ts[ml][f+1] = vy; Ts[ml][f+2] = vz; Ts[ml][f+3] = vw;
  }
  if (!Th) return;
  __syncthreads();
  constexpr int TPR = 256 / FO;       // threads per T-row
  constexpr int EPT = 64 / TPR;       // elems per thread
  const int fr  = tid / TPR;
  const int seg = tid % TPR;
  const int mb  = seg * EPT;
  unsigned short hs[EPT], ls[EPT];
#pragma unroll
  for (int i = 0; i < EPT; ++i) split2(Ts[mb + i][fr], hs[i], ls[i]);
#pragma unroll
  for (int c = 0; c < EPT / 8; ++c) {
    int base = m0 + mb + c * 8;
    if (base + 8 <= M) {
      ushort8v hv, lv;
#pragma unroll
      for (int j = 0; j < 8; ++j) { hv[j] = hs[c*8 + j]; lv[j] = ls[c*8 + j]; }
      *(ushort8v*)(Th + (size_t)fr * ldt + base) = hv;
      *(ushort8v*)(Tl + (size_t)fr * ldt + base) = lv;
    } else {
#pragma unroll
      for (int j = 0; j < 8; ++j) {
        int m = base + j;
        if (m < M) { Th[(size_t)fr * ldt + m] = hs[c*8 + j];
                     Tl[(size_t)fr * ldt + m] = ls[c*8 + j]; }
      }
    }
  }
}

// ---- standalone split-transpose for f32 (N x 32) inputs (x0, x1) ----------
__global__ void splitT32(const float* __restrict__ V, int N,
                         unsigned short* __restrict__ Th, unsigned short* __restrict__ Tl) {
  __shared__ float Ts[64][36];
  const int tid = threadIdx.x;
  const int n0 = blockIdx.x * 64;
#pragma unroll
  for (int p = 0; p < 2; ++p) {
    int e  = p * 1024 + tid * 4;
    int nl = e >> 5;
    int f  = e & 31;
    float4 v = make_float4(0,0,0,0);
    if (n0 + nl < N) v = *(const float4*)(V + (size_t)(n0 + nl) * 32 + f);
    Ts[nl][f+0] = v.x; Ts[nl][f+1] = v.y; Ts[nl][f+2] = v.z; Ts[nl][f+3] = v.w;
  }
  __syncthreads();
  const int fr  = tid >> 3;
  const int seg = tid & 7;
  const int mb  = seg * 8;
  unsigned short hs[8], ls[8];
#pragma unroll
  for (int i = 0; i < 8; ++i) split2(Ts[mb + i][fr], hs[i], ls[i]);
  int base = n0 + mb;
  if (base + 8 <= N) {
    ushort8v hv, lv;
#pragma unroll
    for (int j = 0; j < 8; ++j) { hv[j] = hs[j]; lv[j] = ls[j]; }
    *(ushort8v*)(Th + (size_t)fr * N + base) = hv;
    *(ushort8v*)(Tl + (size_t)fr * N + base) = lv;
  } else {
#pragma unroll
    for (int j = 0; j < 8; ++j) {
      int m = base + j;
      if (m < N) { Th[(size_t)fr * N + m] = hs[j]; Tl[(size_t)fr * N + m] = ls[j]; }
    }
  }
}

// ---- fused channel-mix + relu ---------------------------------------------
__global__ void einsum_relu(const float* __restrict__ XcA, int ldA,
                            const float* __restrict__ XcB, int ldB,
                            const float* __restrict__ C1,
                            const float* __restrict__ C2,
                            const float* __restrict__ Wt,
                            float* __restrict__ out, int N) {
  __shared__ float Ws[32 * 32 * 6];
  for (int i = threadIdx.x; i < 32 * 32 * 6; i += 256) Ws[i] = Wt[i];
  __syncthreads();
  const int n = blockIdx.x * 8 + (threadIdx.x >> 5);
  const int o = threadIdx.x & 31;
  if (n >= N) return;
  const float* xa = XcA + (size_t)n * ldA;
  const float* xb = XcB + (size_t)n * ldB;
  const float* c1 = C1 + (size_t)n * 64;
  const float* c2 = C2 + (size_t)n * 64;
  float acc = 0.f;
#pragma unroll 8
  for (int i = 0; i < 32; ++i) {
    const float* w = Ws + (i * 32 + o) * 6;
    acc = fmaf(xa[i],      w[0], acc);
    acc = fmaf(c1[i],      w[1], acc);
    acc = fmaf(c2[i],      w[2], acc);
    acc = fmaf(xb[i],      w[3], acc);
    acc = fmaf(c1[i + 32], w[4], acc);
    acc = fmaf(c2[i + 32], w[5], acc);
  }
  out[(size_t)n * 32 + o] = fmaxf(acc, 0.f);
}

// ---------------------------------------------------------------------------
extern "C" void kernel_launch(void* const* d_in, const int* in_sizes, int n_in,
                              void* d_out, int out_size, void* d_ws, size_t ws_size,
                              hipStream_t stream) {
  const float* x0  = (const float*)d_in[0];
  const float* x1  = (const float*)d_in[1];
  const float* B1  = (const float*)d_in[2];
  const float* L0  = (const float*)d_in[3];
  const float* L1l = (const float*)d_in[4];
  const float* D1  = (const float*)d_in[5];
  const float* D2  = (const float*)d_in[6];
  const float* W0  = (const float*)d_in[7];
  const float* W1  = (const float*)d_in[8];
  float* out = (float*)d_out;

  // ---- workspace carve (≈40 MB) ----
  float* ws  = (float*)d_ws;
  float* P    = ws;                  // 5,120,000 (max: 8*10000*64)
  float* RHS  = P    + 5120000;      // 3000*64
  float* Y8   = RHS  + 192000;
  float* C10  = Y8   + 192000;
  float* C20  = C10  + 192000;
  float* W_   = C20  + 192000;       // 10000*32
  float* V1   = W_   + 320000;
  float* C11  = V1   + 320000;       // 10000*64
  float* C21  = C11  + 640000;
  unsigned short* U = (unsigned short*)(C21 + 640000);
  unsigned short* x0t_h  = U;              unsigned short* x0t_l  = x0t_h  + 96000;   // 32x3000
  unsigned short* x1t_h  = x0t_l + 96000;  unsigned short* x1t_l  = x1t_h  + 320000;  // 32x10000
  unsigned short* RHSt_h = x1t_l + 320000; unsigned short* RHSt_l = RHSt_h + 192000;  // 64x3000
  unsigned short* Yt_h   = RHSt_l + 192000; unsigned short* Yt_l  = Yt_h   + 192000;  // 64x3000
  unsigned short* C10t_h = Yt_l  + 192000; unsigned short* C10t_l = C10t_h + 192000;  // 64x3000
  unsigned short* Wt_h   = C10t_l + 192000; unsigned short* Wt_l  = Wt_h   + 320000;  // 32x10000
  unsigned short* V1t_h  = Wt_l  + 320000; unsigned short* V1t_l  = V1t_h  + 320000;  // 32x10000
  unsigned short* C11t_h = V1t_l + 320000; unsigned short* C11t_l = C11t_h + 640000;  // 64x10000

  const dim3 blk(256);
  const dim3 gblk(128);               // gemm_sp: 2 waves/block
  const int M0 = 3000, M1 = 10000;
  const int GX0 = (M0 + 127) / 128;   // 24
  const int GX1 = (M1 + 127) / 128;   // 79

  // 1) pre-split x0, x1
  splitT32<<<dim3(47), blk, 0, stream>>>(x0, M0, x0t_h, x0t_l);
  splitT32<<<dim3(157), blk, 0, stream>>>(x1, M1, x1t_h, x1t_l);

  // 2) RHS = [B1@x1 | x0]   (M=3000, K=10000, F=32, KS=16, kchunk=640)
  gemm_sp<32, false, false><<<dim3(GX0, 16), gblk, 0, stream>>>(
      B1, 10000, M0, 10000, x1t_h, x1t_l, nullptr, nullptr, 10000, P, 640);
  reduce_splitT<64><<<dim3(47), blk, 0, stream>>>(
      P, 32, 16, M0, 1.f, nullptr, 0, x0, 32, 1.f, RHS, RHSt_h, RHSt_l, M0);

  // 3) Richardson x8: Y <- RHS + (I - D1) @ Y   (M=K=3000, F=64, KS=16, kchunk=192)
  for (int it = 0; it < 8; ++it) {
    const unsigned short* sh = (it == 0) ? RHSt_h : Yt_h;
    const unsigned short* sl = (it == 0) ? RHSt_l : Yt_l;
    gemm_sp<64, false, true><<<dim3(GX0, 16), gblk, 0, stream>>>(
        D1, 3000, M0, 3000, sh, sl, sh + 32 * 3000, sl + 32 * 3000, 3000, P, 192);
    reduce_splitT<64><<<dim3(47), blk, 0, stream>>>(
        P, 64, 16, M0, 1.f, RHS, 64, RHS + 32, 64, 1.f,
        (it == 7) ? Y8 : nullptr, Yt_h, Yt_l, M0);
  }
  // Yt rows 0..31 = x0p^T, rows 32..63 = z^T; Y8 f32 = [x0p | z]

  // 4) C10 = L0 @ [x0 | x0p]
  gemm_sp<64, false, false><<<dim3(GX0, 16), gblk, 0, stream>>>(
      L0, 3000, M0, 3000, x0t_h, x0t_l, Yt_h, Yt_l, 3000, P, 192);
  reduce_splitT<64><<<dim3(47), blk, 0, stream>>>(
      P, 64, 16, M0, 1.f, nullptr, 0, nullptr, 0, 0.f, C10, C10t_h, C10t_l, M0);

  // 5) C20 = 2*L0@C10 - [x0 | x0p]
  gemm_sp<64, false, false><<<dim3(GX0, 16), gblk, 0, stream>>>(
      L0, 3000, M0, 3000, C10t_h, C10t_l, C10t_h + 32 * 3000, C10t_l + 32 * 3000, 3000, P, 192);
  reduce_splitT<64><<<dim3(47), blk, 0, stream>>>(
      P, 64, 16, M0, 2.f, x0, 32, Y8, 64, -1.f, C20, nullptr, nullptr, M0);

  // 6) W = B1^T @ z   (M=10000, K=3000, F=32, KS=8, kchunk=384, strided A)
  gemm_sp<32, true, false><<<dim3(GX1, 8), gblk, 0, stream>>>(
      B1, 10000, M1, 3000, Yt_h + 32 * 3000, Yt_l + 32 * 3000, nullptr, nullptr, 3000, P, 384);
  reduce_splitT<32><<<dim3(157), blk, 0, stream>>>(
      P, 32, 8, M1, 1.f, nullptr, 0, nullptr, 0, 0.f, W_, Wt_h, Wt_l, M1);

  // 7) V1 = D2 @ W   (M=K=10000, F=32, KS=8, kchunk=1280)
  gemm_sp<32, false, false><<<dim3(GX1, 8), gblk, 0, stream>>>(
      D2, 10000, M1, 10000, Wt_h, Wt_l, nullptr, nullptr, 10000, P, 1280);
  reduce_splitT<32><<<dim3(157), blk, 0, stream>>>(
      P, 32, 8, M1, 1.f, nullptr, 0, nullptr, 0, 0.f, V1, V1t_h, V1t_l, M1);

  // 8) C11 = L1l @ [V1 | x1]
  gemm_sp<64, false, false><<<dim3(GX1, 8), gblk, 0, stream>>>(
      L1l, 10000, M1, 10000, V1t_h, V1t_l, x1t_h, x1t_l, 10000, P, 1280);
  reduce_splitT<64><<<dim3(157), blk, 0, stream>>>(
      P, 64, 8, M1, 1.f, nullptr, 0, nullptr, 0, 0.f, C11, C11t_h, C11t_l, M1);

  // 9) C21 = 2*L1l@C11 - [V1 | x1]
  gemm_sp<64, false, false><<<dim3(GX1, 8), gblk, 0, stream>>>(
      L1l, 10000, M1, 10000, C11t_h, C11t_l, C11t_h + 32 * 10000, C11t_l + 32 * 10000, 10000, P, 1280);
  reduce_splitT<64><<<dim3(157), blk, 0, stream>>>(
      P, 64, 8, M1, 2.f, V1, 32, x1, 32, -1.f, C21, nullptr, nullptr, M1);

  // 10) outputs
  einsum_relu<<<dim3(375), blk, 0, stream>>>(x0, 32, Y8, 64, C10, C20, W0, out, M0);
  einsum_relu<<<dim3(1250), blk, 0, stream>>>(V1, 32, x1, 32, C11, C21, W1, out + (size_t)M0 * 32, M1);
}